// Round 1
// baseline (6802.387 us; speedup 1.0000x reference)
//
#include <hip/hip_runtime.h>
#include <math.h>

// Fused TowersMLP pipeline, fp32 baseline.
// Block = 256 threads processes 16 rows. All intermediates in LDS.
// Thread decomposition: r = tid & 15 (row), s = tid >> 4 (output slice).
// Weights read from global (L2-resident, lane-uniform within s-groups),
// activations from LDS (strides chosen: mult-of-4 for float4 alignment,
// <=2-way bank aliasing which is free on gfx950).

#define ROWS 16

__device__ __forceinline__ float silu_f(float v) {
    return v / (1.0f + __expf(-v));
}

// Generic dense layer: out[r][o] = act( sum_k W[o][k]*in[r][k] + bias[o] (+bias2[o]) )
// o handled by thread s as o = o0 + 16*j, o0 = s, s+64, ...
template<int ACT, int ADD, int B2>
__device__ __forceinline__ void layer_f(
    const float* __restrict__ W, const float* __restrict__ bias,
    const float* in, int in_stride, float* out, int out_stride,
    int N, int K, int r, int s, const float* __restrict__ bias2)
{
    const float* inr = in + r * in_stride;
    float* outr = out + r * out_stride;
    for (int o0 = s; o0 < N; o0 += 64) {
        int nj = (N - o0 + 15) >> 4; nj = nj > 4 ? 4 : nj;
        float acc0 = 0.f, acc1 = 0.f, acc2 = 0.f, acc3 = 0.f;
        const float* w0 = W + (long)o0 * K;
        if (nj == 4) {
            const float* w1 = w0 + 16 * K;
            const float* w2 = w0 + 32 * K;
            const float* w3 = w0 + 48 * K;
            for (int k = 0; k < K; k += 4) {
                float4 a  = *(const float4*)(inr + k);
                float4 b0 = *(const float4*)(w0 + k);
                float4 b1 = *(const float4*)(w1 + k);
                float4 b2 = *(const float4*)(w2 + k);
                float4 b3 = *(const float4*)(w3 + k);
                acc0 += a.x*b0.x + a.y*b0.y + a.z*b0.z + a.w*b0.w;
                acc1 += a.x*b1.x + a.y*b1.y + a.z*b1.z + a.w*b1.w;
                acc2 += a.x*b2.x + a.y*b2.y + a.z*b2.z + a.w*b2.w;
                acc3 += a.x*b3.x + a.y*b3.y + a.z*b3.z + a.w*b3.w;
            }
        } else {
            for (int k = 0; k < K; k += 4) {
                float4 a  = *(const float4*)(inr + k);
                float4 b0 = *(const float4*)(w0 + k);
                acc0 += a.x*b0.x + a.y*b0.y + a.z*b0.z + a.w*b0.w;
                if (nj > 1) {
                    float4 b1 = *(const float4*)(w0 + 16*K + k);
                    acc1 += a.x*b1.x + a.y*b1.y + a.z*b1.z + a.w*b1.w;
                }
                if (nj > 2) {
                    float4 b2 = *(const float4*)(w0 + 32*K + k);
                    acc2 += a.x*b2.x + a.y*b2.y + a.z*b2.z + a.w*b2.w;
                }
            }
        }
        float accs[4] = {acc0, acc1, acc2, acc3};
        #pragma unroll
        for (int j = 0; j < 4; ++j) {
            if (j < nj) {
                int o = o0 + 16 * j;
                float v = accs[j] + bias[o];
                if (B2) v += bias2[o];
                if (ACT) v = silu_f(v);
                if (ADD) outr[o] += v; else outr[o] = v;
            }
        }
    }
}

// LDS float layout:
//   chunks : [16][204]  (chunk c at +c*68)        @ 0      size 3264
//   arenaA : 3264 floats                           @ 3264
//            (xs[16][92]+digits[16][76] | a_ln/f/attn_o [16][204] | hh1[16][164])
//   arenaB : 9408 floats                           @ 6528
//            (hA[16][260]+hB[16][260] | qkv[16][588] | g1[16][396] | flat[16][196]+hh2[16][68])
#define LDS_TOTAL (3264 + 3264 + 9408)

__global__ __launch_bounds__(256, 2)
void towers_fused(const float* __restrict__ x,
                  const float* __restrict__ w_emb, const float* __restrict__ pos_d,
                  const float* __restrict__ pos_c,
                  const float* __restrict__ tw1, const float* __restrict__ tb1,
                  const float* __restrict__ tw2, const float* __restrict__ tb2,
                  const float* __restrict__ tw3, const float* __restrict__ tb3,
                  const float* __restrict__ ln1g, const float* __restrict__ ln1b,
                  const float* __restrict__ inpw, const float* __restrict__ inpb,
                  const float* __restrict__ outw, const float* __restrict__ outb,
                  const float* __restrict__ ln2g, const float* __restrict__ ln2b,
                  const float* __restrict__ ffw1, const float* __restrict__ ffb1,
                  const float* __restrict__ ffw2, const float* __restrict__ ffb2,
                  const float* __restrict__ hw1, const float* __restrict__ hb1,
                  const float* __restrict__ hw2, const float* __restrict__ hb2,
                  const float* __restrict__ hw3, const float* __restrict__ hb3,
                  float* __restrict__ out)
{
    __shared__ float lds[LDS_TOTAL];
    float* chunks = lds;           // [16][204]
    float* arenaA = lds + 3264;
    float* arenaB = lds + 6528;

    const int tid = threadIdx.x;
    const int r = tid & 15;
    const int s = tid >> 4;
    const long long row0 = (long long)blockIdx.x * ROWS;

    // ---- load x rows into LDS ----
    float* xs = arenaA;            // [16][92]
    {
        const float* gx = x + row0 * 90;
        for (int i = tid; i < ROWS * 90; i += 256) {
            int rr = i / 90, cc = i - rr * 90;
            xs[rr * 92 + cc] = gx[i];
        }
    }
    __syncthreads();

    float* digits = arenaA + 16 * 92;   // [16][76]
    float* hA = arenaB;                 // [16][260]
    float* hB = arenaB + 16 * 260;      // [16][260]

    // ---- tower, per chunk ----
    for (int c = 0; c < 3; ++c) {
        // digits: 72 outputs, K=10 per digit group
        for (int o = s; o < 72; o += 16) {
            int gl = o / 24, jj = o - gl * 24;
            int g = c * 3 + gl;
            float acc = pos_d[g * 24 + jj];
            const float* wrow = w_emb + jj * 10;
            const float* xr = xs + r * 92 + g * 10;
            #pragma unroll
            for (int k = 0; k < 10; ++k) acc += xr[k] * wrow[k];
            digits[r * 76 + o] = acc;
        }
        __syncthreads();
        layer_f<1,0,0>(tw1, tb1, digits, 76, hA, 260, 256, 72, r, s, nullptr);
        __syncthreads();
        layer_f<1,0,0>(tw2, tb2, hA, 260, hB, 260, 256, 256, r, s, nullptr);
        __syncthreads();
        layer_f<0,0,1>(tw3, tb3, hB, 260, chunks + c * 68, 204, 64, 256, r, s, pos_c + c * 64);
        __syncthreads();
    }

    // ---- ln1: chunks -> a_ln (arenaA) ----
    float* aln = arenaA;           // [16][204]
    if (tid < 48) {
        int rr = tid & 15, cc = tid >> 4;
        const float* cp = chunks + rr * 204 + cc * 68;
        float sum = 0.f;
        for (int d = 0; d < 64; ++d) sum += cp[d];
        float mu = sum * (1.0f / 64.0f);
        float var = 0.f;
        for (int d = 0; d < 64; ++d) { float t = cp[d] - mu; var += t * t; }
        float rstd = rsqrtf(var * (1.0f / 64.0f) + 1e-5f);
        float* ap = aln + rr * 204 + cc * 68;
        for (int d = 0; d < 64; ++d) ap[d] = (cp[d] - mu) * rstd * ln1g[d] + ln1b[d];
    }
    __syncthreads();

    // ---- qkv: [16][3][192] in arenaB ----
    float* qkv = arenaB;           // [16][588], chunk c at +c*196
    for (int c = 0; c < 3; ++c)
        layer_f<0,0,0>(inpw, inpb, aln + c * 68, 204, qkv + c * 196, 588, 192, 64, r, s, nullptr);
    __syncthreads();

    // ---- attention: 16 rows x 4 heads x 3 query-positions ----
    float* attn_o = arenaA;        // overwrite aln, [16][204]
    if (tid < 192) {
        int rr = tid & 15;
        int hc = tid >> 4;          // 0..11
        int h = hc & 3, cq = hc >> 2;
        const float* base = qkv + rr * 588;
        const float* qv = base + cq * 196 + h * 16;
        float sc0 = 0.f, sc1 = 0.f, sc2 = 0.f;
        const float* k0 = base + 0 * 196 + 64 + h * 16;
        const float* k1 = base + 1 * 196 + 64 + h * 16;
        const float* k2 = base + 2 * 196 + 64 + h * 16;
        #pragma unroll
        for (int dd = 0; dd < 16; ++dd) {
            float q = qv[dd];
            sc0 += q * k0[dd]; sc1 += q * k1[dd]; sc2 += q * k2[dd];
        }
        sc0 *= 0.25f; sc1 *= 0.25f; sc2 *= 0.25f;
        float m = fmaxf(sc0, fmaxf(sc1, sc2));
        float e0 = __expf(sc0 - m), e1 = __expf(sc1 - m), e2 = __expf(sc2 - m);
        float inv = 1.0f / (e0 + e1 + e2);
        e0 *= inv; e1 *= inv; e2 *= inv;
        const float* v0 = base + 0 * 196 + 128 + h * 16;
        const float* v1 = base + 1 * 196 + 128 + h * 16;
        const float* v2 = base + 2 * 196 + 128 + h * 16;
        float* op = attn_o + rr * 204 + cq * 68 + h * 16;
        #pragma unroll
        for (int dd = 0; dd < 16; ++dd) op[dd] = e0 * v0[dd] + e1 * v1[dd] + e2 * v2[dd];
    }
    __syncthreads();

    // ---- attn_out + residual into chunks ----
    for (int c = 0; c < 3; ++c)
        layer_f<0,1,0>(outw, outb, attn_o + c * 68, 204, chunks + c * 68, 204, 64, 64, r, s, nullptr);
    __syncthreads();

    // ---- ln2: chunks -> f (arenaA) ----
    float* f = arenaA;
    if (tid < 48) {
        int rr = tid & 15, cc = tid >> 4;
        const float* cp = chunks + rr * 204 + cc * 68;
        float sum = 0.f;
        for (int d = 0; d < 64; ++d) sum += cp[d];
        float mu = sum * (1.0f / 64.0f);
        float var = 0.f;
        for (int d = 0; d < 64; ++d) { float t = cp[d] - mu; var += t * t; }
        float rstd = rsqrtf(var * (1.0f / 64.0f) + 1e-5f);
        float* fp = f + rr * 204 + cc * 68;
        for (int d = 0; d < 64; ++d) fp[d] = (cp[d] - mu) * rstd * ln2g[d] + ln2b[d];
    }
    __syncthreads();

    // ---- ffn ----
    float* g1 = arenaB;            // [16][396], chunk c at +c*132
    for (int c = 0; c < 3; ++c)
        layer_f<1,0,0>(ffw1, ffb1, f + c * 68, 204, g1 + c * 132, 396, 128, 64, r, s, nullptr);
    __syncthreads();
    for (int c = 0; c < 3; ++c)
        layer_f<0,1,0>(ffw2, ffb2, g1 + c * 132, 396, chunks + c * 68, 204, 64, 128, r, s, nullptr);
    __syncthreads();

    // ---- head: flatten chunks -> [16][192] contiguous ----
    float* flat = arenaB;          // [16][196]
    for (int i = tid; i < ROWS * 192; i += 256) {
        int rr = i / 192, j = i - rr * 192;
        flat[rr * 196 + j] = chunks[rr * 204 + (j >> 6) * 68 + (j & 63)];
    }
    __syncthreads();

    float* hh1 = arenaA;           // [16][164]
    layer_f<1,0,0>(hw1, hb1, flat, 196, hh1, 164, 160, 192, r, s, nullptr);
    __syncthreads();

    float* hh2 = arenaB + 16 * 196;  // [16][68]
    layer_f<1,0,0>(hw2, hb2, hh1, 164, hh2, 68, 64, 160, r, s, nullptr);
    __syncthreads();

    if (tid < 16) {
        const float* hp = hh2 + tid * 68;
        float acc = hb3[0];
        #pragma unroll 4
        for (int d = 0; d < 64; ++d) acc += hp[d] * hw3[d];
        out[row0 + tid] = acc;
    }
}

extern "C" void kernel_launch(void* const* d_in, const int* in_sizes, int n_in,
                              void* d_out, int out_size, void* d_ws, size_t ws_size,
                              hipStream_t stream) {
    const float* x     = (const float*)d_in[0];
    const float* w_emb = (const float*)d_in[1];
    const float* pos_d = (const float*)d_in[2];
    const float* pos_c = (const float*)d_in[3];
    const float* tw1   = (const float*)d_in[4];
    const float* tb1   = (const float*)d_in[5];
    const float* tw2   = (const float*)d_in[6];
    const float* tb2   = (const float*)d_in[7];
    const float* tw3   = (const float*)d_in[8];
    const float* tb3   = (const float*)d_in[9];
    const float* ln1g  = (const float*)d_in[10];
    const float* ln1b  = (const float*)d_in[11];
    const float* inpw  = (const float*)d_in[12];
    const float* inpb  = (const float*)d_in[13];
    const float* outw  = (const float*)d_in[14];
    const float* outb  = (const float*)d_in[15];
    const float* ln2g  = (const float*)d_in[16];
    const float* ln2b  = (const float*)d_in[17];
    const float* ffw1  = (const float*)d_in[18];
    const float* ffb1  = (const float*)d_in[19];
    const float* ffw2  = (const float*)d_in[20];
    const float* ffb2  = (const float*)d_in[21];
    const float* hw1   = (const float*)d_in[22];
    const float* hb1   = (const float*)d_in[23];
    const float* hw2   = (const float*)d_in[24];
    const float* hb2   = (const float*)d_in[25];
    const float* hw3   = (const float*)d_in[26];
    const float* hb3   = (const float*)d_in[27];
    float* out = (float*)d_out;

    const int B = in_sizes[0] / 90;
    const int grid = B / ROWS;   // B = 131072 -> 8192 blocks

    towers_fused<<<grid, 256, 0, stream>>>(
        x, w_emb, pos_d, pos_c, tw1, tb1, tw2, tb2, tw3, tb3,
        ln1g, ln1b, inpw, inpb, outw, outb, ln2g, ln2b,
        ffw1, ffb1, ffw2, ffb2, hw1, hb1, hw2, hb2, hw3, hb3, out);
}

// Round 2
// 465.010 us; speedup vs baseline: 14.6285x; 14.6285x over previous
//
#include <hip/hip_runtime.h>
#include <math.h>

// Fused TowersMLP pipeline, bf16-MFMA version.
// Block = 256 threads (4 waves) processes 16 rows = 48 chunk-tokens.
// All dense layers via v_mfma_f32_16x16x32_bf16, fp32 accumulate.
// Residual stream (chunks), LayerNorm, softmax, final dot stay fp32.
// Weights pre-packed per launch into d_ws as Bp[k/8][n][8] bf16 so each
// lane's B-fragment is one coalesced 16B global load (L2-resident).
// Activations in LDS [M][K_pad] bf16, pitch == 8 mod 16 elems -> 2-way
// bank alias on ds_read_b128 (free on gfx950 per m136).

typedef short s8v __attribute__((ext_vector_type(8)));
typedef float f4v __attribute__((ext_vector_type(4)));

__device__ __forceinline__ short f2bf(float f) {
    unsigned u = __float_as_uint(f);
    unsigned r = (u + 0x7fffu + ((u >> 16) & 1u)) >> 16;   // RNE
    return (short)r;
}
__device__ __forceinline__ float bf2f(short s) {
    return __uint_as_float(((unsigned)(unsigned short)s) << 16);
}
__device__ __forceinline__ float silu_f(float v) {
    return v / (1.0f + __expf(-v));
}

// ---------------- weight pre-pack: W[N][K] f32 -> Bp[k/8][n][8] bf16 ----------------
// layer table: {src, K, Kp, N, dst_off(elems)}
__global__ void pack_weights(const float* __restrict__ tw1, const float* __restrict__ tw2,
                             const float* __restrict__ tw3, const float* __restrict__ inpw,
                             const float* __restrict__ outw, const float* __restrict__ ffw1,
                             const float* __restrict__ ffw2, const float* __restrict__ hw1,
                             const float* __restrict__ hw2, short* __restrict__ dst)
{
    int L = blockIdx.y;
    const float* W; int K, Kp, N, off;
    switch (L) {
      case 0: W = tw1;  K = 72;  Kp = 96;  N = 256; off = 0;      break;
      case 1: W = tw2;  K = 256; Kp = 256; N = 256; off = 24576;  break;
      case 2: W = tw3;  K = 256; Kp = 256; N = 64;  off = 90112;  break;
      case 3: W = inpw; K = 64;  Kp = 64;  N = 192; off = 106496; break;
      case 4: W = outw; K = 64;  Kp = 64;  N = 64;  off = 118784; break;
      case 5: W = ffw1; K = 64;  Kp = 64;  N = 128; off = 122880; break;
      case 6: W = ffw2; K = 128; Kp = 128; N = 64;  off = 131072; break;
      case 7: W = hw1;  K = 192; Kp = 192; N = 160; off = 139264; break;
      default:W = hw2;  K = 160; Kp = 160; N = 64;  off = 169984; break;
    }
    int total = Kp * N;
    for (int e = blockIdx.x * blockDim.x + threadIdx.x; e < total; e += gridDim.x * blockDim.x) {
        int k8 = e / (N * 8);
        int rem = e - k8 * (N * 8);
        int n = rem >> 3, kj = rem & 7;
        int k = k8 * 8 + kj;
        float v = (k < K) ? W[n * K + k] : 0.0f;
        dst[off + e] = f2bf(v);
    }
}

// ---------------- generic MFMA dense layer ----------------
// A: LDS bf16 [rows][Ap], rows = MT*16 tokens. Bp: packed weights (global).
// EPI: 0 = silu -> bf16 LDS out, 1 = linear -> bf16 LDS out,
//      2 = f32 LDS +=,          3 = f32 LDS = v + pos_c[(row%3)*64+col]
template<int MT, int KS, int EPI>
__device__ __forceinline__ void mfma_layer(
    const short* __restrict__ Bp, const float* __restrict__ bias,
    const short* A, int Ap, void* Out, int Op, int N,
    const float* __restrict__ posc, int lane, int wid)
{
    const int l15 = lane & 15, l4 = lane >> 4;
    s8v a[MT][KS];
    #pragma unroll
    for (int m = 0; m < MT; ++m)
        #pragma unroll
        for (int ks = 0; ks < KS; ++ks)
            a[m][ks] = *(const s8v*)(A + (m * 16 + l15) * Ap + ks * 32 + l4 * 8);

    for (int nt = wid; nt < (N >> 4); nt += 4) {
        const int col = nt * 16 + l15;
        s8v b[KS];
        #pragma unroll
        for (int ks = 0; ks < KS; ++ks)
            b[ks] = *(const s8v*)(Bp + ((ks * 4 + l4) * N + col) * 8);
        float bv = bias[col];
        #pragma unroll
        for (int m = 0; m < MT; ++m) {
            f4v acc = {0.f, 0.f, 0.f, 0.f};
            #pragma unroll
            for (int ks = 0; ks < KS; ++ks)
                acc = __builtin_amdgcn_mfma_f32_16x16x32_bf16(a[m][ks], b[ks], acc, 0, 0, 0);
            #pragma unroll
            for (int i = 0; i < 4; ++i) {
                int row = m * 16 + l4 * 4 + i;
                float v = acc[i] + bv;
                if (EPI == 0)      ((short*)Out)[row * Op + col] = f2bf(silu_f(v));
                else if (EPI == 1) ((short*)Out)[row * Op + col] = f2bf(v);
                else if (EPI == 2) ((float*)Out)[row * Op + col] += v;
                else               ((float*)Out)[row * Op + col] = v + posc[(row % 3) * 64 + col];
            }
        }
    }
}

// ---------------- LDS layout (63744 B) ----------------
// CH  @ 0      : f32 [48][68]          = 13056 B   (residual stream, persistent)
// P   @ 13056  : 25344 B arena  (H1 | aln/f/flat @+0 | attn_o @+7168 | hh2 @+8192)
// Q   @ 38400  : 25344 B arena  (xs@0, A1@5888, wemb@15872, posd@16832 | H2 | qkv | g1 | hh1)
#define CH_OFF 0
#define P_OFF  13056
#define Q_OFF  38400
#define LDS_BYTES 63744

__global__ __launch_bounds__(256, 2)
void towers_mfma(const float* __restrict__ x,
                 const float* __restrict__ w_emb, const float* __restrict__ pos_d,
                 const float* __restrict__ pos_c,
                 const float* __restrict__ tb1, const float* __restrict__ tb2,
                 const float* __restrict__ tb3,
                 const float* __restrict__ ln1g, const float* __restrict__ ln1b,
                 const float* __restrict__ inpb, const float* __restrict__ outb,
                 const float* __restrict__ ln2g, const float* __restrict__ ln2b,
                 const float* __restrict__ ffb1, const float* __restrict__ ffb2,
                 const float* __restrict__ hb1, const float* __restrict__ hb2,
                 const float* __restrict__ hw3, const float* __restrict__ hb3,
                 const short* __restrict__ wsBp,
                 float* __restrict__ out)
{
    __shared__ __align__(16) char smem[LDS_BYTES];
    float* CH = (float*)(smem + CH_OFF);     // [48][68]
    char* P = smem + P_OFF;
    char* Q = smem + Q_OFF;

    const int tid = threadIdx.x;
    const int lane = tid & 63, wid = tid >> 6;
    const long long row0 = (long long)blockIdx.x * 16;

    // ---- stage x, w_emb, pos_d ----
    float* xs    = (float*)Q;                // [16][92]
    short* A1    = (short*)(Q + 5888);       // [48][104], Kp=96
    float* wembs = (float*)(Q + 15872);      // [24][10]
    float* posds = (float*)(Q + 16832);      // [9][24]
    {
        const float* gx = x + row0 * 90;
        for (int i = tid; i < 1440; i += 256) xs[(i / 90) * 92 + (i % 90)] = gx[i];
        for (int i = tid; i < 240; i += 256) wembs[i] = w_emb[i];
        for (int i = tid; i < 216; i += 256) posds[i] = pos_d[i];
    }
    __syncthreads();

    // ---- digits -> A1 bf16 (token t = r*3+c, col o = gl*24+jj) ----
    for (int task = tid; task < 3456; task += 256) {
        int t = task / 72, o = task - t * 72;
        int r = t / 3, c = t - r * 3;
        int gl = o / 24, jj = o - gl * 24;
        int g = c * 3 + gl;
        float acc = posds[g * 24 + jj];
        const float* xr = xs + r * 92 + g * 10;
        const float* wr = wembs + jj * 10;
        #pragma unroll
        for (int k = 0; k < 10; ++k) acc += xr[k] * wr[k];
        A1[t * 104 + o] = f2bf(acc);
    }
    for (int i = tid; i < 1152; i += 256) A1[(i / 24) * 104 + 72 + (i % 24)] = 0;
    __syncthreads();

    // ---- tower ----
    short* H1 = (short*)P;                   // [48][264]
    short* H2 = (short*)Q;                   // [48][264]
    mfma_layer<3, 3, 0>(wsBp + 0,      tb1, A1, 104, H1, 264, 256, nullptr, lane, wid);
    __syncthreads();
    mfma_layer<3, 8, 0>(wsBp + 24576,  tb2, H1, 264, H2, 264, 256, nullptr, lane, wid);
    __syncthreads();
    mfma_layer<3, 8, 3>(wsBp + 90112,  tb3, H2, 264, CH, 68, 64, pos_c, lane, wid);
    __syncthreads();

    // ---- ln1 -> aln bf16 ----
    short* aln = (short*)P;                  // [48][72]
    if (tid < 48) {
        const float* cp = CH + tid * 68;
        float s = 0.f;
        for (int d = 0; d < 64; ++d) s += cp[d];
        float mu = s * (1.0f / 64.0f);
        float var = 0.f;
        for (int d = 0; d < 64; ++d) { float t2 = cp[d] - mu; var += t2 * t2; }
        float rstd = rsqrtf(var * (1.0f / 64.0f) + 1e-5f);
        short* ap = aln + tid * 72;
        for (int d = 0; d < 64; ++d) ap[d] = f2bf((cp[d] - mu) * rstd * ln1g[d] + ln1b[d]);
    }
    __syncthreads();

    // ---- qkv ----
    short* qkv = (short*)Q;                  // [48][200]
    mfma_layer<3, 2, 1>(wsBp + 106496, inpb, aln, 72, qkv, 200, 192, nullptr, lane, wid);
    __syncthreads();

    // ---- attention (fp32 on bf16 qkv) ----
    short* ao = (short*)(P + 7168);          // [48][72]
    if (tid < 192) {
        int r = tid & 15, hc = tid >> 4;
        int h = hc & 3, cq = hc >> 2;
        const short* qp = qkv + (r * 3 + cq) * 200 + h * 16;
        float qv[16];
        { s8v q0 = *(const s8v*)qp, q1 = *(const s8v*)(qp + 8);
          #pragma unroll
          for (int j = 0; j < 8; ++j) { qv[j] = bf2f(q0[j]); qv[8 + j] = bf2f(q1[j]); } }
        float sc[3];
        #pragma unroll
        for (int c = 0; c < 3; ++c) {
            const short* kp = qkv + (r * 3 + c) * 200 + 64 + h * 16;
            s8v k0 = *(const s8v*)kp, k1 = *(const s8v*)(kp + 8);
            float acc = 0.f;
            #pragma unroll
            for (int j = 0; j < 8; ++j) acc += qv[j] * bf2f(k0[j]) + qv[8 + j] * bf2f(k1[j]);
            sc[c] = acc * 0.25f;
        }
        float m = fmaxf(sc[0], fmaxf(sc[1], sc[2]));
        float e0 = __expf(sc[0] - m), e1 = __expf(sc[1] - m), e2 = __expf(sc[2] - m);
        float inv = 1.0f / (e0 + e1 + e2);
        e0 *= inv; e1 *= inv; e2 *= inv;
        float ov[16];
        #pragma unroll
        for (int j = 0; j < 16; ++j) ov[j] = 0.f;
        const float ee[3] = {e0, e1, e2};
        #pragma unroll
        for (int c = 0; c < 3; ++c) {
            const short* vp = qkv + (r * 3 + c) * 200 + 128 + h * 16;
            s8v v0 = *(const s8v*)vp, v1 = *(const s8v*)(vp + 8);
            #pragma unroll
            for (int j = 0; j < 8; ++j) { ov[j] += ee[c] * bf2f(v0[j]); ov[8 + j] += ee[c] * bf2f(v1[j]); }
        }
        short* op = ao + (r * 3 + cq) * 72 + h * 16;
        s8v o0, o1;
        #pragma unroll
        for (int j = 0; j < 8; ++j) { o0[j] = f2bf(ov[j]); o1[j] = f2bf(ov[8 + j]); }
        *(s8v*)op = o0; *(s8v*)(op + 8) = o1;
    }
    __syncthreads();

    // ---- attn out proj, += residual ----
    mfma_layer<3, 2, 2>(wsBp + 118784, outb, ao, 72, CH, 68, 64, nullptr, lane, wid);
    __syncthreads();

    // ---- ln2 -> f bf16 ----
    short* fb = (short*)P;                   // [48][72]
    if (tid < 48) {
        const float* cp = CH + tid * 68;
        float s = 0.f;
        for (int d = 0; d < 64; ++d) s += cp[d];
        float mu = s * (1.0f / 64.0f);
        float var = 0.f;
        for (int d = 0; d < 64; ++d) { float t2 = cp[d] - mu; var += t2 * t2; }
        float rstd = rsqrtf(var * (1.0f / 64.0f) + 1e-5f);
        short* fp = fb + tid * 72;
        for (int d = 0; d < 64; ++d) fp[d] = f2bf((cp[d] - mu) * rstd * ln2g[d] + ln2b[d]);
    }
    __syncthreads();

    // ---- ffn ----
    short* g1 = (short*)Q;                   // [48][136]
    mfma_layer<3, 2, 0>(wsBp + 122880, ffb1, fb, 72, g1, 136, 128, nullptr, lane, wid);
    __syncthreads();
    mfma_layer<3, 4, 2>(wsBp + 131072, ffb2, g1, 136, CH, 68, 64, nullptr, lane, wid);
    __syncthreads();

    // ---- flatten chunks -> flat bf16 [16][200] ----
    short* flat = (short*)P;
    for (int i = tid; i < 3072; i += 256) {
        int r = i / 192, j = i - r * 192;
        flat[r * 200 + j] = f2bf(CH[(r * 3 + (j >> 6)) * 68 + (j & 63)]);
    }
    __syncthreads();

    // ---- head ----
    short* hh1 = (short*)Q;                  // [16][168]
    mfma_layer<1, 6, 0>(wsBp + 139264, hb1, flat, 200, hh1, 168, 160, nullptr, lane, wid);
    __syncthreads();
    short* hh2 = (short*)(P + 8192);         // [16][72]
    mfma_layer<1, 5, 0>(wsBp + 169984, hb2, hh1, 168, hh2, 72, 64, nullptr, lane, wid);
    __syncthreads();

    if (tid < 16) {
        float acc = hb3[0];
        const short* hp = hh2 + tid * 72;
        #pragma unroll 4
        for (int d = 0; d < 64; ++d) acc += bf2f(hp[d]) * hw3[d];
        out[row0 + tid] = acc;
    }
}

extern "C" void kernel_launch(void* const* d_in, const int* in_sizes, int n_in,
                              void* d_out, int out_size, void* d_ws, size_t ws_size,
                              hipStream_t stream) {
    const float* x     = (const float*)d_in[0];
    const float* w_emb = (const float*)d_in[1];
    const float* pos_d = (const float*)d_in[2];
    const float* pos_c = (const float*)d_in[3];
    const float* tw1   = (const float*)d_in[4];
    const float* tb1   = (const float*)d_in[5];
    const float* tw2   = (const float*)d_in[6];
    const float* tb2   = (const float*)d_in[7];
    const float* tw3   = (const float*)d_in[8];
    const float* tb3   = (const float*)d_in[9];
    const float* ln1g  = (const float*)d_in[10];
    const float* ln1b  = (const float*)d_in[11];
    const float* inpw  = (const float*)d_in[12];
    const float* inpb  = (const float*)d_in[13];
    const float* outw  = (const float*)d_in[14];
    const float* outb  = (const float*)d_in[15];
    const float* ln2g  = (const float*)d_in[16];
    const float* ln2b  = (const float*)d_in[17];
    const float* ffw1  = (const float*)d_in[18];
    const float* ffb1  = (const float*)d_in[19];
    const float* ffw2  = (const float*)d_in[20];
    const float* ffb2  = (const float*)d_in[21];
    const float* hw1   = (const float*)d_in[22];
    const float* hb1   = (const float*)d_in[23];
    const float* hw2   = (const float*)d_in[24];
    const float* hb2   = (const float*)d_in[25];
    const float* hw3   = (const float*)d_in[26];
    const float* hb3   = (const float*)d_in[27];
    float* out = (float*)d_out;
    short* wsBp = (short*)d_ws;              // needs 360448 B

    // pre-pack weights (runs each launch; deterministic; ~180K elems)
    pack_weights<<<dim3(32, 9), 256, 0, stream>>>(tw1, tw2, tw3, inpw, outw,
                                                  ffw1, ffw2, hw1, hw2, wsBp);

    const int B = in_sizes[0] / 90;
    towers_mfma<<<B / 16, 256, 0, stream>>>(
        x, w_emb, pos_d, pos_c, tb1, tb2, tb3,
        ln1g, ln1b, inpb, outb, ln2g, ln2b,
        ffb1, ffb2, hb1, hb2, hw3, hb3, wsBp, out);
}

// Round 3
// 347.989 us; speedup vs baseline: 19.5477x; 1.3363x over previous
//
#include <hip/hip_runtime.h>
#include <math.h>

// Fused TowersMLP pipeline, bf16-MFMA, 3-blocks/CU version.
// Block = 256 threads (4 waves) processes 16 rows = 48 chunk-tokens.
// All dense layers via v_mfma_f32_16x16x32_bf16, fp32 accumulate.
// LDS = two 25344B ping-pong arenas (50688B total -> 3 blocks/CU).
// LayerNorm + final dot parallelized with shfl reduces.

typedef short s8v __attribute__((ext_vector_type(8)));
typedef float f4v __attribute__((ext_vector_type(4)));

__device__ __forceinline__ short f2bf(float f) {
    unsigned u = __float_as_uint(f);
    unsigned r = (u + 0x7fffu + ((u >> 16) & 1u)) >> 16;   // RNE
    return (short)r;
}
__device__ __forceinline__ float bf2f(short s) {
    return __uint_as_float(((unsigned)(unsigned short)s) << 16);
}
__device__ __forceinline__ float silu_f(float v) {
    return v / (1.0f + __expf(-v));
}

// ---------------- weight pre-pack: W[N][K] f32 -> Bp[k/8][n][8] bf16 ----------------
__global__ void pack_weights(const float* __restrict__ tw1, const float* __restrict__ tw2,
                             const float* __restrict__ tw3, const float* __restrict__ inpw,
                             const float* __restrict__ outw, const float* __restrict__ ffw1,
                             const float* __restrict__ ffw2, const float* __restrict__ hw1,
                             const float* __restrict__ hw2, short* __restrict__ dst)
{
    int L = blockIdx.y;
    const float* W; int K, Kp, N, off;
    switch (L) {
      case 0: W = tw1;  K = 72;  Kp = 96;  N = 256; off = 0;      break;
      case 1: W = tw2;  K = 256; Kp = 256; N = 256; off = 24576;  break;
      case 2: W = tw3;  K = 256; Kp = 256; N = 64;  off = 90112;  break;
      case 3: W = inpw; K = 64;  Kp = 64;  N = 192; off = 106496; break;
      case 4: W = outw; K = 64;  Kp = 64;  N = 64;  off = 118784; break;
      case 5: W = ffw1; K = 64;  Kp = 64;  N = 128; off = 122880; break;
      case 6: W = ffw2; K = 128; Kp = 128; N = 64;  off = 131072; break;
      case 7: W = hw1;  K = 192; Kp = 192; N = 160; off = 139264; break;
      default:W = hw2;  K = 160; Kp = 160; N = 64;  off = 169984; break;
    }
    int total = Kp * N;
    for (int e = blockIdx.x * blockDim.x + threadIdx.x; e < total; e += gridDim.x * blockDim.x) {
        int k8 = e / (N * 8);
        int rem = e - k8 * (N * 8);
        int n = rem >> 3, kj = rem & 7;
        int k = k8 * 8 + kj;
        float v = (k < K) ? W[n * K + k] : 0.0f;
        dst[off + e] = f2bf(v);
    }
}

// ---------------- generic MFMA dense layer ----------------
// EPI: 0 = silu -> bf16 LDS out, 1 = linear -> bf16 LDS out,
//      2 = f32 LDS +=,          3 = f32 LDS = v + pos_c[(row%3)*64+col]
template<int MT, int KS, int EPI>
__device__ __forceinline__ void mfma_layer(
    const short* __restrict__ Bp, const float* __restrict__ bias,
    const short* A, int Ap, void* Out, int Op, int N,
    const float* __restrict__ posc, int lane, int wid)
{
    const int l15 = lane & 15, l4 = lane >> 4;
    s8v a[MT][KS];
    #pragma unroll
    for (int m = 0; m < MT; ++m)
        #pragma unroll
        for (int ks = 0; ks < KS; ++ks)
            a[m][ks] = *(const s8v*)(A + (m * 16 + l15) * Ap + ks * 32 + l4 * 8);

    for (int nt = wid; nt < (N >> 4); nt += 4) {
        const int col = nt * 16 + l15;
        s8v b[KS];
        #pragma unroll
        for (int ks = 0; ks < KS; ++ks)
            b[ks] = *(const s8v*)(Bp + ((ks * 4 + l4) * N + col) * 8);
        float bv = bias[col];
        #pragma unroll
        for (int m = 0; m < MT; ++m) {
            f4v acc = {0.f, 0.f, 0.f, 0.f};
            #pragma unroll
            for (int ks = 0; ks < KS; ++ks)
                acc = __builtin_amdgcn_mfma_f32_16x16x32_bf16(a[m][ks], b[ks], acc, 0, 0, 0);
            #pragma unroll
            for (int i = 0; i < 4; ++i) {
                int row = m * 16 + l4 * 4 + i;
                float v = acc[i] + bv;
                if (EPI == 0)      ((short*)Out)[row * Op + col] = f2bf(silu_f(v));
                else if (EPI == 1) ((short*)Out)[row * Op + col] = f2bf(v);
                else if (EPI == 2) ((float*)Out)[row * Op + col] += v;
                else               ((float*)Out)[row * Op + col] = v + posc[(row % 3) * 64 + col];
            }
        }
    }
}

// ---------------- LDS: two ping-pong arenas of 25344 B ----------------
#define ARENA 25344
#define LDS_BYTES (2 * ARENA)

__global__ __launch_bounds__(256, 3)
void towers_mfma(const float* __restrict__ x,
                 const float* __restrict__ w_emb, const float* __restrict__ pos_d,
                 const float* __restrict__ pos_c,
                 const float* __restrict__ tb1, const float* __restrict__ tb2,
                 const float* __restrict__ tb3,
                 const float* __restrict__ ln1g, const float* __restrict__ ln1b,
                 const float* __restrict__ inpb, const float* __restrict__ outb,
                 const float* __restrict__ ln2g, const float* __restrict__ ln2b,
                 const float* __restrict__ ffb1, const float* __restrict__ ffb2,
                 const float* __restrict__ hb1, const float* __restrict__ hb2,
                 const float* __restrict__ hw3, const float* __restrict__ hb3,
                 const short* __restrict__ wsBp,
                 float* __restrict__ out)
{
    __shared__ __align__(16) char smem[LDS_BYTES];
    char* P = smem;
    char* Q = smem + ARENA;

    const int tid = threadIdx.x;
    const int lane = tid & 63, wid = tid >> 6;
    const long long row0 = (long long)blockIdx.x * 16;

    // ---- phase 1: stage x, w_emb, pos_d (Q); A1 in P ----
    float* xs    = (float*)Q;                // [16][92]  f32
    float* wembs = (float*)(Q + 5888);       // [24][10]
    float* posds = (float*)(Q + 6848);       // [9][24]
    short* A1    = (short*)P;                // [48][104] bf16, Kp=96
    {
        const float* gx = x + row0 * 90;
        for (int i = tid; i < 1440; i += 256) xs[(i / 90) * 92 + (i % 90)] = gx[i];
        for (int i = tid; i < 240; i += 256) wembs[i] = w_emb[i];
        for (int i = tid; i < 216; i += 256) posds[i] = pos_d[i];
    }
    __syncthreads();

    // ---- digits -> A1 bf16 (token t = r*3+c, col o = gl*24+jj) ----
    for (int task = tid; task < 3456; task += 256) {
        int t = task / 72, o = task - t * 72;
        int r = t / 3, c = t - r * 3;
        int gl = o / 24, jj = o - gl * 24;
        int g = c * 3 + gl;
        float acc = posds[g * 24 + jj];
        const float* xr = xs + r * 92 + g * 10;
        const float* wr = wembs + jj * 10;
        #pragma unroll
        for (int k = 0; k < 10; ++k) acc += xr[k] * wr[k];
        A1[t * 104 + o] = f2bf(acc);
    }
    for (int i = tid; i < 1152; i += 256) A1[(i / 24) * 104 + 72 + (i % 24)] = 0;
    __syncthreads();

    // ---- tower: A1(P) -> H1(Q) -> H2(P) -> CH(Q) ----
    short* H1 = (short*)Q;                   // [48][264] = 25344 B
    short* H2 = (short*)P;                   // [48][264]
    float* CH = (float*)Q;                   // [48][68] f32 = 13056 B
    mfma_layer<3, 3, 0>(wsBp + 0,      tb1, A1, 104, H1, 264, 256, nullptr, lane, wid);
    __syncthreads();
    mfma_layer<3, 8, 0>(wsBp + 24576,  tb2, H1, 264, H2, 264, 256, nullptr, lane, wid);
    __syncthreads();
    mfma_layer<3, 8, 3>(wsBp + 90112,  tb3, H2, 264, CH, 68, 64, pos_c, lane, wid);
    __syncthreads();

    // ---- ln1 -> aln bf16 (Q tail), parallel: 4 threads/token ----
    short* aln = (short*)(Q + 13056);        // [48][72]
    if (tid < 192) {
        int t = tid >> 2, p = tid & 3;
        const float* cp = CH + t * 68 + p * 16;
        float s = 0.f, ss = 0.f;
        #pragma unroll
        for (int d = 0; d < 16; ++d) { float v = cp[d]; s += v; ss += v * v; }
        s  += __shfl_xor(s, 1);  ss += __shfl_xor(ss, 1);
        s  += __shfl_xor(s, 2);  ss += __shfl_xor(ss, 2);
        float mu = s * (1.0f / 64.0f);
        float var = ss * (1.0f / 64.0f) - mu * mu;
        float rstd = rsqrtf(var + 1e-5f);
        short* ap = aln + t * 72 + p * 16;
        #pragma unroll
        for (int d = 0; d < 16; ++d) {
            int dd = p * 16 + d;
            ap[d] = f2bf((cp[d] - mu) * rstd * ln1g[dd] + ln1b[dd]);
        }
    }
    __syncthreads();

    // ---- qkv: aln(Q tail) -> qkv(P) ----
    short* qkv = (short*)P;                  // [48][200]
    mfma_layer<3, 2, 1>(wsBp + 106496, inpb, aln, 72, qkv, 200, 192, nullptr, lane, wid);
    __syncthreads();

    // ---- attention -> ao (Q tail, over aln) ----
    short* ao = (short*)(Q + 13056);         // [48][72]
    if (tid < 192) {
        int r = tid & 15, hc = tid >> 4;
        int h = hc & 3, cq = hc >> 2;
        const short* qp = qkv + (r * 3 + cq) * 200 + h * 16;
        float qv[16];
        { s8v q0 = *(const s8v*)qp, q1 = *(const s8v*)(qp + 8);
          #pragma unroll
          for (int j = 0; j < 8; ++j) { qv[j] = bf2f(q0[j]); qv[8 + j] = bf2f(q1[j]); } }
        float sc[3];
        #pragma unroll
        for (int c = 0; c < 3; ++c) {
            const short* kp = qkv + (r * 3 + c) * 200 + 64 + h * 16;
            s8v k0 = *(const s8v*)kp, k1 = *(const s8v*)(kp + 8);
            float acc = 0.f;
            #pragma unroll
            for (int j = 0; j < 8; ++j) acc += qv[j] * bf2f(k0[j]) + qv[8 + j] * bf2f(k1[j]);
            sc[c] = acc * 0.25f;
        }
        float m = fmaxf(sc[0], fmaxf(sc[1], sc[2]));
        float e0 = __expf(sc[0] - m), e1 = __expf(sc[1] - m), e2 = __expf(sc[2] - m);
        float inv = 1.0f / (e0 + e1 + e2);
        e0 *= inv; e1 *= inv; e2 *= inv;
        float ov[16];
        #pragma unroll
        for (int j = 0; j < 16; ++j) ov[j] = 0.f;
        const float ee[3] = {e0, e1, e2};
        #pragma unroll
        for (int c = 0; c < 3; ++c) {
            const short* vp = qkv + (r * 3 + c) * 200 + 128 + h * 16;
            s8v v0 = *(const s8v*)vp, v1 = *(const s8v*)(vp + 8);
            #pragma unroll
            for (int j = 0; j < 8; ++j) { ov[j] += ee[c] * bf2f(v0[j]); ov[8 + j] += ee[c] * bf2f(v1[j]); }
        }
        short* op = ao + (r * 3 + cq) * 72 + h * 16;
        s8v o0, o1;
        #pragma unroll
        for (int j = 0; j < 8; ++j) { o0[j] = f2bf(ov[j]); o1[j] = f2bf(ov[8 + j]); }
        *(s8v*)op = o0; *(s8v*)(op + 8) = o1;
    }
    __syncthreads();

    // ---- attn out proj, += residual CH ----
    mfma_layer<3, 2, 2>(wsBp + 118784, outb, ao, 72, CH, 68, 64, nullptr, lane, wid);
    __syncthreads();

    // ---- ln2 -> fb (Q tail, over ao), parallel ----
    short* fb = (short*)(Q + 13056);         // [48][72]
    if (tid < 192) {
        int t = tid >> 2, p = tid & 3;
        const float* cp = CH + t * 68 + p * 16;
        float s = 0.f, ss = 0.f;
        #pragma unroll
        for (int d = 0; d < 16; ++d) { float v = cp[d]; s += v; ss += v * v; }
        s  += __shfl_xor(s, 1);  ss += __shfl_xor(ss, 1);
        s  += __shfl_xor(s, 2);  ss += __shfl_xor(ss, 2);
        float mu = s * (1.0f / 64.0f);
        float var = ss * (1.0f / 64.0f) - mu * mu;
        float rstd = rsqrtf(var + 1e-5f);
        short* fp = fb + t * 72 + p * 16;
        #pragma unroll
        for (int d = 0; d < 16; ++d) {
            int dd = p * 16 + d;
            fp[d] = f2bf((cp[d] - mu) * rstd * ln2g[dd] + ln2b[dd]);
        }
    }
    __syncthreads();

    // ---- ffn: fb -> g1(P, over qkv) -> += CH ----
    short* g1 = (short*)P;                   // [48][136] = 13056 B
    mfma_layer<3, 2, 0>(wsBp + 122880, ffb1, fb, 72, g1, 136, 128, nullptr, lane, wid);
    __syncthreads();
    mfma_layer<3, 4, 2>(wsBp + 131072, ffb2, g1, 136, CH, 68, 64, nullptr, lane, wid);
    __syncthreads();

    // ---- flatten CH -> flat bf16 [16][200] (P @13312) ----
    short* flat = (short*)(P + 13312);
    for (int i = tid; i < 3072; i += 256) {
        int r = i / 192, j = i - r * 192;
        flat[r * 200 + j] = f2bf(CH[(r * 3 + (j >> 6)) * 68 + (j & 63)]);
    }
    __syncthreads();

    // ---- head ----
    short* hh1 = (short*)(Q + 13056);        // [16][168] (over fb)
    mfma_layer<1, 6, 0>(wsBp + 139264, hb1, flat, 200, hh1, 168, 160, nullptr, lane, wid);
    __syncthreads();
    short* hh2 = (short*)P;                  // [16][72]
    mfma_layer<1, 5, 0>(wsBp + 169984, hb2, hh1, 168, hh2, 72, 64, nullptr, lane, wid);
    __syncthreads();

    // ---- final dot, parallel: 4 threads/row + shfl reduce ----
    if (tid < 64) {
        int r = tid >> 2, p = tid & 3;
        const short* hp = hh2 + r * 72 + p * 16;
        float acc = 0.f;
        #pragma unroll
        for (int d = 0; d < 16; ++d) acc += bf2f(hp[d]) * hw3[p * 16 + d];
        acc += __shfl_xor(acc, 1);
        acc += __shfl_xor(acc, 2);
        if (p == 0) out[row0 + r] = acc + hb3[0];
    }
}

extern "C" void kernel_launch(void* const* d_in, const int* in_sizes, int n_in,
                              void* d_out, int out_size, void* d_ws, size_t ws_size,
                              hipStream_t stream) {
    const float* x     = (const float*)d_in[0];
    const float* w_emb = (const float*)d_in[1];
    const float* pos_d = (const float*)d_in[2];
    const float* pos_c = (const float*)d_in[3];
    const float* tw1   = (const float*)d_in[4];
    const float* tb1   = (const float*)d_in[5];
    const float* tw2   = (const float*)d_in[6];
    const float* tb2   = (const float*)d_in[7];
    const float* tw3   = (const float*)d_in[8];
    const float* tb3   = (const float*)d_in[9];
    const float* ln1g  = (const float*)d_in[10];
    const float* ln1b  = (const float*)d_in[11];
    const float* inpw  = (const float*)d_in[12];
    const float* inpb  = (const float*)d_in[13];
    const float* outw  = (const float*)d_in[14];
    const float* outb  = (const float*)d_in[15];
    const float* ln2g  = (const float*)d_in[16];
    const float* ln2b  = (const float*)d_in[17];
    const float* ffw1  = (const float*)d_in[18];
    const float* ffb1  = (const float*)d_in[19];
    const float* ffw2  = (const float*)d_in[20];
    const float* ffb2  = (const float*)d_in[21];
    const float* hw1   = (const float*)d_in[22];
    const float* hb1   = (const float*)d_in[23];
    const float* hw2   = (const float*)d_in[24];
    const float* hb2   = (const float*)d_in[25];
    const float* hw3   = (const float*)d_in[26];
    const float* hb3   = (const float*)d_in[27];
    float* out = (float*)d_out;
    short* wsBp = (short*)d_ws;              // needs 360448 B

    pack_weights<<<dim3(32, 9), 256, 0, stream>>>(tw1, tw2, tw3, inpw, outw,
                                                  ffw1, ffw2, hw1, hw2, wsBp);

    const int B = in_sizes[0] / 90;
    towers_mfma<<<B / 16, 256, 0, stream>>>(
        x, w_emb, pos_d, pos_c, tb1, tb2, tb3,
        ln1g, ln1b, inpb, outb, ln2g, ln2b,
        ffb1, ffb2, hb1, hb2, hw3, hb3, wsBp, out);
}